// Round 11
// baseline (40.476 us; speedup 1.0000x reference)
//
#include <hip/hip_runtime.h>
#include <hip/hip_fp8.h>

#define NN 4096
#define DD 512
#define CC 1000
#define NB 64   // 64x64 tiles -> triangle grid 64*65/2 = 2080 blocks
#define REP 4   // DIAGNOSTIC: repeat GEMM phase so kmain tops the rocprof table

typedef __attribute__((ext_vector_type(4))) float f32x4;
typedef __attribute__((ext_vector_type(4))) int i32x4;
typedef __attribute__((ext_vector_type(8))) int i32x8;

// ---------------- kernel 1: normalize rows -> fp8 e4m3 X, init out ---------
__global__ __launch_bounds__(256) void knorm(const float* __restrict__ embs,
                                             unsigned char* __restrict__ Xq,
                                             float* __restrict__ out) {
  int tid = threadIdx.x;
  if (blockIdx.x == 0 && tid == 0) out[0] = 0.f;  // stream-ordered before kmain
  int lane = tid & 63;
  int row = blockIdx.x * 4 + (tid >> 6);
  const float* rp = embs + (size_t)row * DD;
  float4 v0 = ((const float4*)rp)[lane * 2];
  float4 v1 = ((const float4*)rp)[lane * 2 + 1];
  float ss = v0.x * v0.x + v0.y * v0.y + v0.z * v0.z + v0.w * v0.w +
             v1.x * v1.x + v1.y * v1.y + v1.z * v1.z + v1.w * v1.w;
  for (int off = 32; off; off >>= 1) ss += __shfl_xor(ss, off);
  float scale = 1.0f / fmaxf(sqrtf(ss), 1e-8f);
  float f[8] = {v0.x, v0.y, v0.z, v0.w, v1.x, v1.y, v1.z, v1.w};
  unsigned long long o = 0;
#pragma unroll
  for (int i = 0; i < 8; ++i) {
    __hip_fp8_e4m3 q(f[i] * scale);  // OCP e4m3fn, RNE
    o |= (unsigned long long)q.__x << (8 * i);
  }
  *(unsigned long long*)(Xq + (size_t)row * DD + lane * 8) = o;
}

// ---------------- kernel 2: R10 structure + REP diagnostic loop -------------
// IDENTICAL geometry/arithmetic to R10 (triangular fp8-MX 64x64 tiles).
// The GEMM phase runs REP times; between reps the accumulator is scaled by an
// OPAQUE zero (inline-asm v_mov, invisible to the optimizer -> no DCE of the
// earlier reps, rule #17) so the final acc -- and the output -- are
// bit-identical to R10 while kmain's duration ~4x its GEMM steady-state,
// pushing it past the harness fills into the rocprof top-5 so we finally see
// MfmaUtil / VALUBusy / Occupancy / FETCH_SIZE / LDS_BANK_CONFLICT.
__global__ __launch_bounds__(256) void kmain(const unsigned char* __restrict__ Xq,
                                             const int* __restrict__ labels,
                                             const float* __restrict__ Aij,
                                             float* __restrict__ out) {
  __shared__ __align__(16) unsigned char As[64 * 128];  // 64 rows x 128B (BK=128)
  __shared__ __align__(16) unsigned char Bs[64 * 128];
  int tid = threadIdx.x;
  int lane = tid & 63;
  int w = tid >> 6;
  int wr = w >> 1, wc = w & 1;

  // decode triangular block index: by = row-block, bx in [by, NB)
  int t = blockIdx.x;
  int by = 0;
  while (t >= (NB - by)) { t -= (NB - by); ++by; }
  int bx = by + t;
  int row0 = by * 64;
  int col0 = bx * 64;

  f32x4 acc[2][2];
#pragma unroll
  for (int m = 0; m < 2; ++m)
#pragma unroll
    for (int n = 0; n < 2; ++n) acc[m][n] = (f32x4){0.f, 0.f, 0.f, 0.f};

  const int SC1 = 0x7F7F7F7F;  // e8m0 = 127 -> scale 1.0, all byte lanes

  float zz;
  asm volatile("v_mov_b32 %0, 0" : "=v"(zz));  // opaque 0.0 (keeps reps live)

  for (int rep = 0; rep < REP; ++rep) {
    if (rep) {
#pragma unroll
      for (int m = 0; m < 2; ++m)
#pragma unroll
        for (int n = 0; n < 2; ++n) {
          acc[m][n][0] *= zz; acc[m][n][1] *= zz;
          acc[m][n][2] *= zz; acc[m][n][3] *= zz;
        }
      __syncthreads();  // prior rep's LDS readers done before restaging
    }

    for (int it = 0; it < DD / 128; ++it) {  // 4 K-steps of 128 fp8
      int k0 = it * 128;
      if (it) __syncthreads();
#pragma unroll
      for (int i = 0; i < 2; ++i) {
        int idx = i * 256 + tid;              // 16B chunk index
        int r = idx >> 3;                     // tile row (128B per row)
        int c = idx & 7;                      // 16B chunk within row
        int srcB = ((c ^ (r & 7)) << 4);      // inverse-swizzled source byte
        const unsigned char* ga = Xq + (size_t)(row0 + r) * DD + k0 + srcB;
        const unsigned char* gb = Xq + (size_t)(col0 + r) * DD + k0 + srcB;
        __builtin_amdgcn_global_load_lds(
            (const __attribute__((address_space(1))) void*)ga,
            (__attribute__((address_space(3))) void*)(As + idx * 16), 16, 0, 0);
        __builtin_amdgcn_global_load_lds(
            (const __attribute__((address_space(1))) void*)gb,
            (__attribute__((address_space(3))) void*)(Bs + idx * 16), 16, 0, 0);
      }
      __syncthreads();

      // one K=128 scaled MFMA per fragment pair
      int o2 = (lane >> 4) << 1;              // first logical 16B-chunk
      i32x8 a[2], b[2];
#pragma unroll
      for (int m = 0; m < 2; ++m) {
        int r = wr * 32 + m * 16 + (lane & 15);
        const unsigned char* base = As + r * 128;
        i32x4 lo = *(const i32x4*)(base + ((o2 ^ (r & 7)) << 4));
        i32x4 hi = *(const i32x4*)(base + (((o2 + 1) ^ (r & 7)) << 4));
        a[m][0] = lo[0]; a[m][1] = lo[1]; a[m][2] = lo[2]; a[m][3] = lo[3];
        a[m][4] = hi[0]; a[m][5] = hi[1]; a[m][6] = hi[2]; a[m][7] = hi[3];
      }
#pragma unroll
      for (int n = 0; n < 2; ++n) {
        int r = wc * 32 + n * 16 + (lane & 15);
        const unsigned char* base = Bs + r * 128;
        i32x4 lo = *(const i32x4*)(base + ((o2 ^ (r & 7)) << 4));
        i32x4 hi = *(const i32x4*)(base + (((o2 + 1) ^ (r & 7)) << 4));
        b[n][0] = lo[0]; b[n][1] = lo[1]; b[n][2] = lo[2]; b[n][3] = lo[3];
        b[n][4] = hi[0]; b[n][5] = hi[1]; b[n][6] = hi[2]; b[n][7] = hi[3];
      }
#pragma unroll
      for (int m = 0; m < 2; ++m)
#pragma unroll
        for (int n = 0; n < 2; ++n)
          acc[m][n] = __builtin_amdgcn_mfma_scale_f32_16x16x128_f8f6f4(
              a[m], b[n], acc[m][n], 0 /*cbsz: fp8*/, 0 /*blgp: fp8*/,
              0, SC1, 0, SC1);
    }
  }

  // fused epilogue: gate on d_emb first (rarely true off-diagonal) so gathers
  // stay behind an exec-masked branch; per-element triangle/mirror rule.
  float lsum = 0.f;
#pragma unroll
  for (int m = 0; m < 2; ++m) {
#pragma unroll
    for (int n = 0; n < 2; ++n) {
#pragma unroll
      for (int jv = 0; jv < 4; ++jv) {
        float s = acc[m][n][jv];
        float de = 1.0f - s;
        if (de < 0.7f) {
          int row = row0 + wr * 32 + m * 16 + ((lane >> 4) * 4 + jv);
          int col = col0 + wc * 32 + n * 16 + (lane & 15);
          if (col >= row) {
            int lr = labels[row], lc = labels[col];
            float dc = Aij[lr * CC + lc];
            if (dc < 0.7f) {
              float d = de - dc;
              lsum += d * d;
            }
            if (col > row) {  // mirrored ordered pair (col,row)
              float dc2 = Aij[lc * CC + lr];
              if (dc2 < 0.7f) {
                float d = de - dc2;
                lsum += d * d;
              }
            }
          }
        }
      }
    }
  }
  for (int off = 32; off; off >>= 1) lsum += __shfl_xor(lsum, off);
  __shared__ float red[4];
  if ((tid & 63) == 0) red[w] = lsum;
  __syncthreads();
  if (tid == 0) {
    float v = (red[0] + red[1] + red[2] + red[3]) * (1.0f / ((float)NN * (float)NN));
    if (v != 0.f) atomicAdd(out, v);
  }
}

extern "C" void kernel_launch(void* const* d_in, const int* in_sizes, int n_in,
                              void* d_out, int out_size, void* d_ws, size_t ws_size,
                              hipStream_t stream) {
  const float* embs = (const float*)d_in[0];
  const int* labels = (const int*)d_in[1];
  const float* Aij = (const float*)d_in[2];
  float* out = (float*)d_out;
  unsigned char* Xq = (unsigned char*)d_ws;  // 4096*512 fp8 = 2 MB

  knorm<<<NN / 4, 256, 0, stream>>>(embs, Xq, out);            // fills Xq, zeroes out
  kmain<<<(NB * (NB + 1)) / 2, 256, 0, stream>>>(Xq, labels, Aij, out);  // triangle
}

// Round 12
// 30.204 us; speedup vs baseline: 1.3401x; 1.3401x over previous
//
#include <hip/hip_runtime.h>
#include <hip/hip_fp8.h>

#define NN 4096
#define DD 512
#define CC 1000
#define NB 64   // 64 row/col panels of 64 -> triangle = 64*65/2 = 2080 wave-tiles

typedef __attribute__((ext_vector_type(4))) float f32x4;

// ---------------- kernel 1: normalize -> fp8, PACK into 512B frag tiles -----
// Pack layout: tile (p, c) covers rows [p*16, p*16+16) x k-bytes [c*32, c*32+32),
// stored at ((p*16)+c)*512; within the tile, MFMA-lane fl = (row&15) + 16*ksub
// (ksub = (kbyte>>3)&3) holds its 8 bytes contiguously at fl*8 -- EXACTLY the
// mfma_f32_16x16x32_fp8_fp8 A/B fragment (same mapping R7's LDS reads used,
// proven absmax 1.19e-7). kmain's fragment load = ONE coalesced
// global_load_dwordx2 (64 lanes x 8B = 512B contiguous).
__global__ __launch_bounds__(256) void knorm(const float* __restrict__ embs,
                                             unsigned char* __restrict__ Xq,
                                             float* __restrict__ out) {
  int tid = threadIdx.x;
  if (blockIdx.x == 0 && tid == 0) out[0] = 0.f;  // stream-ordered before kmain
  int lane = tid & 63;
  int row = blockIdx.x * 4 + (tid >> 6);
  const float* rp = embs + (size_t)row * DD;
  float4 v0 = ((const float4*)rp)[lane * 2];
  float4 v1 = ((const float4*)rp)[lane * 2 + 1];
  float ss = v0.x * v0.x + v0.y * v0.y + v0.z * v0.z + v0.w * v0.w +
             v1.x * v1.x + v1.y * v1.y + v1.z * v1.z + v1.w * v1.w;
  for (int off = 32; off; off >>= 1) ss += __shfl_xor(ss, off);
  float scale = 1.0f / fmaxf(sqrtf(ss), 1e-8f);
  float f[8] = {v0.x, v0.y, v0.z, v0.w, v1.x, v1.y, v1.z, v1.w};
  unsigned long long o = 0;
#pragma unroll
  for (int i = 0; i < 8; ++i) {
    __hip_fp8_e4m3 q(f[i] * scale);  // OCP e4m3fn, RNE
    o |= (unsigned long long)q.__x << (8 * i);
  }
  // lane holds row bytes [8*lane, 8*lane+8): chunk c = lane>>2, ksub = lane&3
  size_t addr = ((size_t)(row >> 4) * 16 + (lane >> 2)) * 512 +
                (size_t)((row & 15) + 16 * (lane & 3)) * 8;
  *(unsigned long long*)(Xq + addr) = o;
}

// ---------------- kernel 2: barrier-free LDS-free per-wave fp8 GEMM ---------
// R11 PMC showed the LDS pipe (write + double-read + 33% conflicts) IS the
// bottleneck (~640cy/block-it ~= whole kernel). Staged data has zero multicast
// value here, so: each WAVE computes one 64x64 triangle tile reading fragments
// DIRECTLY from the packed global layout (L2-resident, 2MB). 16 K-chunks of
// 32; 3-parity named register buffers, full unroll (static indices),
// sched_barrier(0) pins each 8-load issue group ahead of the MFMAs so the
// compiler can't sink loads to uses (R6's collapse). ~130 VGPR -> 3 waves/SIMD
// -> all 2080 waves resident; L2 port ~56B/cy/CU is the intended binder.
__global__ __launch_bounds__(256) void kmain(const unsigned char* __restrict__ Xq,
                                             const int* __restrict__ labels,
                                             const float* __restrict__ Aij,
                                             float* __restrict__ out) {
  int lane = threadIdx.x & 63;
  int wid = blockIdx.x * 4 + (threadIdx.x >> 6);

  // decode triangular tile index: by = row-panel, bx in [by, NB)
  int t = wid;
  int by = 0;
  while (t >= (NB - by)) { t -= (NB - by); ++by; }
  int bx = by + t;
  int row0 = by * 64;
  int col0 = bx * 64;

  // wave-tile 64x64: A row-tiles m = by*4+m, B row-tiles n = bx*4+n.
  // fragment addr(m, c) = (( (by*4+m)*16 + c ))*512 + lane*8
  const unsigned char* baseA = Xq + (size_t)(by * 4) * 8192 + lane * 8;
  const unsigned char* baseB = Xq + (size_t)(bx * 4) * 8192 + lane * 8;

  f32x4 acc[4][4];
#pragma unroll
  for (int m = 0; m < 4; ++m)
#pragma unroll
    for (int n = 0; n < 4; ++n) acc[m][n] = (f32x4){0.f, 0.f, 0.f, 0.f};

  long A[3][4], B[3][4];  // 3-parity chunk buffers (static idx via full unroll)

#define LOADC(buf, c)                                                   \
  {                                                                     \
    _Pragma("unroll") for (int m = 0; m < 4; ++m) {                     \
      A[buf][m] = *(const long*)(baseA + m * 8192 + (c) * 512);         \
      B[buf][m] = *(const long*)(baseB + m * 8192 + (c) * 512);         \
    }                                                                   \
  }

  LOADC(0, 0);
  LOADC(1, 1);
  __builtin_amdgcn_sched_barrier(0);

#pragma unroll
  for (int c = 0; c < 16; ++c) {
    if (c + 2 < 16) {
      const int nb = (c + 2) % 3;
      LOADC(nb, c + 2);                      // issue 2 chunks ahead
      __builtin_amdgcn_sched_barrier(0);     // pin: issue before this MFMA set
    }
    const int cb = c % 3;
#pragma unroll
    for (int m = 0; m < 4; ++m)
#pragma unroll
      for (int n = 0; n < 4; ++n)
        acc[m][n] = __builtin_amdgcn_mfma_f32_16x16x32_fp8_fp8(
            A[cb][m], B[cb][n], acc[m][n], 0, 0, 0);
  }
#undef LOADC

  // fused epilogue: gate on d_emb first (rarely true off-diagonal) so gathers
  // stay behind an exec-masked branch; per-element triangle/mirror rule.
  float lsum = 0.f;
#pragma unroll
  for (int m = 0; m < 4; ++m) {
#pragma unroll
    for (int n = 0; n < 4; ++n) {
#pragma unroll
      for (int jv = 0; jv < 4; ++jv) {
        float s = acc[m][n][jv];
        float de = 1.0f - s;
        if (de < 0.7f) {
          int row = row0 + m * 16 + ((lane >> 4) * 4 + jv);
          int col = col0 + n * 16 + (lane & 15);
          if (col >= row) {
            int lr = labels[row], lc = labels[col];
            float dc = Aij[lr * CC + lc];
            if (dc < 0.7f) {
              float d = de - dc;
              lsum += d * d;
            }
            if (col > row) {  // mirrored ordered pair (col,row)
              float dc2 = Aij[lc * CC + lr];
              if (dc2 < 0.7f) {
                float d = de - dc2;
                lsum += d * d;
              }
            }
          }
        }
      }
    }
  }
  // per-wave reduce + single atomic (almost all waves have lsum==0)
  for (int off = 32; off; off >>= 1) lsum += __shfl_xor(lsum, off);
  if (lane == 0) {
    float v = lsum * (1.0f / ((float)NN * (float)NN));
    if (v != 0.f) atomicAdd(out, v);
  }
}

extern "C" void kernel_launch(void* const* d_in, const int* in_sizes, int n_in,
                              void* d_out, int out_size, void* d_ws, size_t ws_size,
                              hipStream_t stream) {
  const float* embs = (const float*)d_in[0];
  const int* labels = (const int*)d_in[1];
  const float* Aij = (const float*)d_in[2];
  float* out = (float*)d_out;
  unsigned char* Xq = (unsigned char*)d_ws;  // packed fp8 tiles: 2 MB

  knorm<<<NN / 4, 256, 0, stream>>>(embs, Xq, out);  // fills Xq, zeroes out
  int nwaves = (NB * (NB + 1)) / 2;                  // 2080 wave-tiles
  kmain<<<nwaves / 4, 256, 0, stream>>>(Xq, labels, Aij, out);
}

// Round 13
// 24.677 us; speedup vs baseline: 1.6402x; 1.2240x over previous
//
#include <hip/hip_runtime.h>
#include <hip/hip_fp8.h>

#define NN 4096
#define DD 512
#define CC 1000
#define NBT 32  // 32 row/col panels of 128 -> triangle = 32*33/2 = 528 blocks

typedef __attribute__((ext_vector_type(4))) float f32x4;

// ---------------- kernel 1: normalize rows -> fp8 e4m3 X, init out ---------
__global__ __launch_bounds__(256) void knorm(const float* __restrict__ embs,
                                             unsigned char* __restrict__ Xq,
                                             float* __restrict__ out) {
  int tid = threadIdx.x;
  if (blockIdx.x == 0 && tid == 0) out[0] = 0.f;  // stream-ordered before kmain
  int lane = tid & 63;
  int row = blockIdx.x * 4 + (tid >> 6);
  const float* rp = embs + (size_t)row * DD;
  float4 v0 = ((const float4*)rp)[lane * 2];
  float4 v1 = ((const float4*)rp)[lane * 2 + 1];
  float ss = v0.x * v0.x + v0.y * v0.y + v0.z * v0.z + v0.w * v0.w +
             v1.x * v1.x + v1.y * v1.y + v1.z * v1.z + v1.w * v1.w;
  for (int off = 32; off; off >>= 1) ss += __shfl_xor(ss, off);
  float scale = 1.0f / fmaxf(sqrtf(ss), 1e-8f);
  float f[8] = {v0.x, v0.y, v0.z, v0.w, v1.x, v1.y, v1.z, v1.w};
  unsigned long long o = 0;
#pragma unroll
  for (int i = 0; i < 8; ++i) {
    __hip_fp8_e4m3 q(f[i] * scale);  // OCP e4m3fn, RNE
    o |= (unsigned long long)q.__x << (8 * i);
  }
  *(unsigned long long*)(Xq + (size_t)row * DD + lane * 8) = o;
}

// ---------------- kernel 2: triangular fp8 X @ X^T, 128x128 tiles -----------
// R11 decomposition: GEMM marginal ~5.4us, REP-invariant fixed ~17us with all
// pipes idle -> dispatch-ramp hypothesis (~120 blocks/us x 2080). Fix: 4x
// fewer blocks (528) via 128x128 fp8 tiles; each staged byte feeds 2x MFMA
// work so LDS traffic HALVES (R7's proven 2-barrier schedule kept verbatim).
// 4 waves (2x2), each 64x64 out = 4x4 frags of mfma_f32_16x16x32_fp8_fp8.
// Swizzle family proven in R7: stage chunk (r,c) from source byte
// ((c^(r&7))<<4); read chunk q at ((q^(r&7))<<4)|o. Per-element triangle
// rule: col>row -> both ordered terms; col==row -> single; col<row skipped.
__global__ __launch_bounds__(256) void kmain(const unsigned char* __restrict__ Xq,
                                             const int* __restrict__ labels,
                                             const float* __restrict__ Aij,
                                             float* __restrict__ out) {
  __shared__ __align__(16) unsigned char As[128 * 128];  // 16 KB (BK=128)
  __shared__ __align__(16) unsigned char Bs[128 * 128];  // 16 KB
  int tid = threadIdx.x;
  int lane = tid & 63;
  int w = tid >> 6;
  int wr = w >> 1, wc = w & 1;

  // decode triangular block index: by = row-panel, bx in [by, NBT)
  int t = blockIdx.x;
  int by = 0;
  while (t >= (NBT - by)) { t -= (NBT - by); ++by; }
  int bx = by + t;
  int row0 = by * 128;
  int col0 = bx * 128;

  f32x4 acc[4][4];
#pragma unroll
  for (int m = 0; m < 4; ++m)
#pragma unroll
    for (int n = 0; n < 4; ++n) acc[m][n] = (f32x4){0.f, 0.f, 0.f, 0.f};

  for (int it = 0; it < DD / 128; ++it) {  // 4 K-steps of 128 fp8
    int k0 = it * 128;
    if (it) __syncthreads();
#pragma unroll
    for (int i = 0; i < 4; ++i) {
      int idx = i * 256 + tid;              // 16B chunk index (1024 chunks/panel)
      int r = idx >> 3;                     // tile row in [0,128), 128B per row
      int c = idx & 7;                      // 16B chunk within row
      int srcB = ((c ^ (r & 7)) << 4);      // inverse-swizzled source byte
      const unsigned char* ga = Xq + (size_t)(row0 + r) * DD + k0 + srcB;
      const unsigned char* gb = Xq + (size_t)(col0 + r) * DD + k0 + srcB;
      __builtin_amdgcn_global_load_lds(
          (const __attribute__((address_space(1))) void*)ga,
          (__attribute__((address_space(3))) void*)(As + idx * 16), 16, 0, 0);
      __builtin_amdgcn_global_load_lds(
          (const __attribute__((address_space(1))) void*)gb,
          (__attribute__((address_space(3))) void*)(Bs + idx * 16), 16, 0, 0);
    }
    __syncthreads();
#pragma unroll
    for (int ks = 0; ks < 4; ++ks) {        // 4 MFMA k-sub-steps of 32
      int q = (ks << 1) | (lane >> 5);      // 16B-chunk of this lane's 8B
      int o = ((lane >> 4) & 1) << 3;       // 8B half within chunk
      long a[4], b[4];
#pragma unroll
      for (int m = 0; m < 4; ++m) {
        int r = wr * 64 + m * 16 + (lane & 15);
        a[m] = *(const long*)(As + r * 128 + (((q ^ (r & 7)) << 4) | o));
      }
#pragma unroll
      for (int n = 0; n < 4; ++n) {
        int r = wc * 64 + n * 16 + (lane & 15);
        b[n] = *(const long*)(Bs + r * 128 + (((q ^ (r & 7)) << 4) | o));
      }
#pragma unroll
      for (int m = 0; m < 4; ++m)
#pragma unroll
        for (int n = 0; n < 4; ++n)
          acc[m][n] = __builtin_amdgcn_mfma_f32_16x16x32_fp8_fp8(a[m], b[n],
                                                                 acc[m][n], 0, 0, 0);
    }
  }

  // fused epilogue: gate on d_emb first (rarely true off-diagonal) so gathers
  // stay behind an exec-masked branch; per-element triangle/mirror rule.
  float lsum = 0.f;
#pragma unroll
  for (int m = 0; m < 4; ++m) {
#pragma unroll
    for (int n = 0; n < 4; ++n) {
#pragma unroll
      for (int jv = 0; jv < 4; ++jv) {
        float s = acc[m][n][jv];
        float de = 1.0f - s;
        if (de < 0.7f) {
          int row = row0 + wr * 64 + m * 16 + ((lane >> 4) * 4 + jv);
          int col = col0 + wc * 64 + n * 16 + (lane & 15);
          if (col >= row) {
            int lr = labels[row], lc = labels[col];
            float dc = Aij[lr * CC + lc];
            if (dc < 0.7f) {
              float d = de - dc;
              lsum += d * d;
            }
            if (col > row) {  // mirrored ordered pair (col,row)
              float dc2 = Aij[lc * CC + lr];
              if (dc2 < 0.7f) {
                float d = de - dc2;
                lsum += d * d;
              }
            }
          }
        }
      }
    }
  }
  for (int off = 32; off; off >>= 1) lsum += __shfl_xor(lsum, off);
  __shared__ float red[4];
  if ((tid & 63) == 0) red[w] = lsum;
  __syncthreads();
  if (tid == 0) {
    float v = (red[0] + red[1] + red[2] + red[3]) * (1.0f / ((float)NN * (float)NN));
    if (v != 0.f) atomicAdd(out, v);
  }
}

extern "C" void kernel_launch(void* const* d_in, const int* in_sizes, int n_in,
                              void* d_out, int out_size, void* d_ws, size_t ws_size,
                              hipStream_t stream) {
  const float* embs = (const float*)d_in[0];
  const int* labels = (const int*)d_in[1];
  const float* Aij = (const float*)d_in[2];
  float* out = (float*)d_out;
  unsigned char* Xq = (unsigned char*)d_ws;  // 4096*512 fp8 = 2 MB

  knorm<<<NN / 4, 256, 0, stream>>>(embs, Xq, out);            // fills Xq, zeroes out
  kmain<<<(NBT * (NBT + 1)) / 2, 256, 0, stream>>>(Xq, labels, Aij, out);  // triangle
}

// Round 14
// 24.138 us; speedup vs baseline: 1.6769x; 1.0224x over previous
//
#include <hip/hip_runtime.h>
#include <hip/hip_fp8.h>

#define NN 4096
#define DD 512
#define CC 1000
#define NB 64   // 64x64 tiles -> triangle grid 64*65/2 = 2080 blocks

typedef __attribute__((ext_vector_type(4))) float f32x4;

// ---------------- kernel 1: normalize rows -> fp8 e4m3 X, init out ---------
// one wave per row; fp32 sum-of-squares, shuffle reduce, scale, fp8 quantize.
// X is 2 MB: L2-resident on every XCD; halves L2->CU traffic vs bf16.
__global__ __launch_bounds__(256) void knorm(const float* __restrict__ embs,
                                             unsigned char* __restrict__ Xq,
                                             float* __restrict__ out) {
  int tid = threadIdx.x;
  if (blockIdx.x == 0 && tid == 0) out[0] = 0.f;  // stream-ordered before kmain
  int lane = tid & 63;
  int row = blockIdx.x * 4 + (tid >> 6);
  const float* rp = embs + (size_t)row * DD;
  float4 v0 = ((const float4*)rp)[lane * 2];
  float4 v1 = ((const float4*)rp)[lane * 2 + 1];
  float ss = v0.x * v0.x + v0.y * v0.y + v0.z * v0.z + v0.w * v0.w +
             v1.x * v1.x + v1.y * v1.y + v1.z * v1.z + v1.w * v1.w;
  for (int off = 32; off; off >>= 1) ss += __shfl_xor(ss, off);
  float scale = 1.0f / fmaxf(sqrtf(ss), 1e-8f);
  float f[8] = {v0.x, v0.y, v0.z, v0.w, v1.x, v1.y, v1.z, v1.w};
  unsigned long long o = 0;
#pragma unroll
  for (int i = 0; i < 8; ++i) {
    __hip_fp8_e4m3 q(f[i] * scale);  // OCP e4m3fn, RNE
    o |= (unsigned long long)q.__x << (8 * i);
  }
  *(unsigned long long*)(Xq + (size_t)row * DD + lane * 8) = o;
}

// ---------------- kernel 2: triangular fused fp8 X @ X^T -> gated loss ------
// Best-measured configuration (R7, 24.16 us): 64x64 tiles, 2080 triangle
// blocks, BK=128, 2-barrier schedule, global_load_lds(16B) staging with
// both-sides XOR swizzle, mfma_f32_16x16x32_fp8_fp8.
// Per-element triangle rule: col>row -> both ordered terms (mirrored Aij
// gather); col==row -> single term (in-MFMA diagonal); col<row skipped.
__global__ __launch_bounds__(256) void kmain(const unsigned char* __restrict__ Xq,
                                             const int* __restrict__ labels,
                                             const float* __restrict__ Aij,
                                             float* __restrict__ out) {
  __shared__ __align__(16) unsigned char As[64 * 128];  // 64 rows x 128B (BK=128)
  __shared__ __align__(16) unsigned char Bs[64 * 128];
  int tid = threadIdx.x;
  int lane = tid & 63;
  int w = tid >> 6;
  int wr = w >> 1, wc = w & 1;

  // decode triangular block index: by = row-block, bx in [by, NB)
  int t = blockIdx.x;
  int by = 0;
  while (t >= (NB - by)) { t -= (NB - by); ++by; }
  int bx = by + t;
  int row0 = by * 64;
  int col0 = bx * 64;

  f32x4 acc[2][2];
#pragma unroll
  for (int m = 0; m < 2; ++m)
#pragma unroll
    for (int n = 0; n < 2; ++n) acc[m][n] = (f32x4){0.f, 0.f, 0.f, 0.f};

  for (int it = 0; it < DD / 128; ++it) {  // 4 K-steps of 128 fp8
    int k0 = it * 128;
    if (it) __syncthreads();
#pragma unroll
    for (int i = 0; i < 2; ++i) {
      int idx = i * 256 + tid;              // 16B chunk index (512 chunks = 8KB)
      int r = idx >> 3;                     // tile row (128B per row)
      int c = idx & 7;                      // 16B chunk within row
      int srcB = ((c ^ (r & 7)) << 4);      // inverse-swizzled source byte
      const unsigned char* ga = Xq + (size_t)(row0 + r) * DD + k0 + srcB;
      const unsigned char* gb = Xq + (size_t)(col0 + r) * DD + k0 + srcB;
      __builtin_amdgcn_global_load_lds(
          (const __attribute__((address_space(1))) void*)ga,
          (__attribute__((address_space(3))) void*)(As + idx * 16), 16, 0, 0);
      __builtin_amdgcn_global_load_lds(
          (const __attribute__((address_space(1))) void*)gb,
          (__attribute__((address_space(3))) void*)(Bs + idx * 16), 16, 0, 0);
    }
    __syncthreads();
#pragma unroll
    for (int ks = 0; ks < 4; ++ks) {        // 4 MFMA k-sub-steps of 32
      int q = (ks << 1) | (lane >> 5);      // 16B-chunk of this lane's 8B
      int o = ((lane >> 4) & 1) << 3;       // 8B half within chunk
      long a[2], b[2];
#pragma unroll
      for (int m = 0; m < 2; ++m) {
        int r = wr * 32 + m * 16 + (lane & 15);
        a[m] = *(const long*)(As + r * 128 + (((q ^ (r & 7)) << 4) | o));
      }
#pragma unroll
      for (int n = 0; n < 2; ++n) {
        int r = wc * 32 + n * 16 + (lane & 15);
        b[n] = *(const long*)(Bs + r * 128 + (((q ^ (r & 7)) << 4) | o));
      }
#pragma unroll
      for (int m = 0; m < 2; ++m)
#pragma unroll
        for (int n = 0; n < 2; ++n)
          acc[m][n] = __builtin_amdgcn_mfma_f32_16x16x32_fp8_fp8(a[m], b[n],
                                                                 acc[m][n], 0, 0, 0);
    }
  }

  // fused epilogue: gate on d_emb first (rarely true off-diagonal) so gathers
  // stay behind an exec-masked branch; per-element triangle/mirror rule.
  float lsum = 0.f;
#pragma unroll
  for (int m = 0; m < 2; ++m) {
#pragma unroll
    for (int n = 0; n < 2; ++n) {
#pragma unroll
      for (int jv = 0; jv < 4; ++jv) {
        float s = acc[m][n][jv];
        float de = 1.0f - s;
        if (de < 0.7f) {
          int row = row0 + wr * 32 + m * 16 + ((lane >> 4) * 4 + jv);
          int col = col0 + wc * 32 + n * 16 + (lane & 15);
          if (col >= row) {
            int lr = labels[row], lc = labels[col];
            float dc = Aij[lr * CC + lc];
            if (dc < 0.7f) {
              float d = de - dc;
              lsum += d * d;
            }
            if (col > row) {  // mirrored ordered pair (col,row)
              float dc2 = Aij[lc * CC + lr];
              if (dc2 < 0.7f) {
                float d = de - dc2;
                lsum += d * d;
              }
            }
          }
        }
      }
    }
  }
  for (int off = 32; off; off >>= 1) lsum += __shfl_xor(lsum, off);
  __shared__ float red[4];
  if ((tid & 63) == 0) red[w] = lsum;
  __syncthreads();
  if (tid == 0) {
    float v = (red[0] + red[1] + red[2] + red[3]) * (1.0f / ((float)NN * (float)NN));
    if (v != 0.f) atomicAdd(out, v);
  }
}

extern "C" void kernel_launch(void* const* d_in, const int* in_sizes, int n_in,
                              void* d_out, int out_size, void* d_ws, size_t ws_size,
                              hipStream_t stream) {
  const float* embs = (const float*)d_in[0];
  const int* labels = (const int*)d_in[1];
  const float* Aij = (const float*)d_in[2];
  float* out = (float*)d_out;
  unsigned char* Xq = (unsigned char*)d_ws;  // 4096*512 fp8 = 2 MB

  knorm<<<NN / 4, 256, 0, stream>>>(embs, Xq, out);            // fills Xq, zeroes out
  kmain<<<(NB * (NB + 1)) / 2, 256, 0, stream>>>(Xq, labels, Aij, out);  // triangle
}